// Round 5
// baseline (441.001 us; speedup 1.0000x reference)
//
#include <hip/hip_runtime.h>

// Sparsemax along dim=-1 for x[4,4096,4096] fp32.
// tau solves sum(max(x-tau,0)) = 1; Newton on convex piecewise-linear
//   f(tau) = sum_{x>tau}(x) - k*tau - 1:   tau <- (S-1)/k
// from tau0 = max(x)-1 (f(tau0) >= 0, tau increases monotonically, finite
// convergence). KEY: since tau >= tau0 always, only elements > tau0 can
// ever be in the support. For Gaussian rows that's ~14 of 4096. We gather
// them once into a wave-private LDS list, then every lane runs the Newton
// loop serially over that tiny list (identical data -> identical tau in
// all lanes; bit-exact, no per-iteration cross-lane ops at all).
//
// One wave per row; row held in VGPRs (16x float4 per lane).

#define ROW_D 4096
#define BLOCK 256          // 4 waves/block, 1 row per wave
#define WPB   (BLOCK / 64)
#define NV    16           // float4 per lane: 64 elements/lane
#define CAP   128          // candidate slots per wave (fallback if exceeded)

__global__ __launch_bounds__(BLOCK)
void sparsemax_wave_kernel(const float* __restrict__ x,
                           float* __restrict__ out) {
    const int wave = threadIdx.x >> 6;
    const int lane = threadIdx.x & 63;
    const size_t row = (size_t)blockIdx.x * WPB + wave;

    __shared__ __align__(16) float s_cand[WPB][CAP];
    __shared__ int s_cnt[WPB];

    // Wave-private init. Same-wave DS ops execute in program order, and the
    // __syncthreads() below orders everything before the Newton reads.
    if (lane == 0) s_cnt[wave] = 0;
    s_cand[wave][lane]      = -1e30f;   // padding: never > tau
    s_cand[wave][lane + 64] = -1e30f;

    const float* __restrict__ xr   = x   + row * ROW_D;
    float*       __restrict__ outr = out + row * ROW_D;

    // ---- load 64 elements per lane, coalesced float4 ----
    float4 v[NV];
#pragma unroll
    for (int j = 0; j < NV; ++j)
        v[j] = reinterpret_cast<const float4*>(xr)[lane + j * 64];

    // ---- row max: register tree + one shfl_xor butterfly ----
    float m = fmaxf(fmaxf(v[0].x, v[0].y), fmaxf(v[0].z, v[0].w));
#pragma unroll
    for (int j = 1; j < NV; ++j)
        m = fmaxf(m, fmaxf(fmaxf(v[j].x, v[j].y), fmaxf(v[j].z, v[j].w)));
#pragma unroll
    for (int off = 1; off < 64; off <<= 1)
        m = fmaxf(m, __shfl_xor(m, off, 64));

    const float tau0 = m - 1.0f;

    // ---- scatter candidates (> tau0) into wave-private LDS list ----
    // Rare (exec-masked branch is false for ~all lanes at each position).
#pragma unroll
    for (int j = 0; j < NV; ++j) {
        const float a[4] = {v[j].x, v[j].y, v[j].z, v[j].w};
#pragma unroll
        for (int q = 0; q < 4; ++q) {
            if (a[q] > tau0) {
                int slot = atomicAdd(&s_cnt[wave], 1);
                if (slot < CAP) s_cand[wave][slot] = a[q];
            }
        }
    }

    __syncthreads();   // order scatter vs reads (also compiler fence)

    const int K = s_cnt[wave];
    float tau = tau0;

    if (K <= CAP) {
        // ---- serial Newton over the tiny candidate list ----
        // All lanes compute identically (same LDS data, same order) ->
        // tau is wave-uniform and the break is bit-exact.
        const int K4 = (K + 3) & ~3;   // padded slots are -1e30
        for (int it = 0; it < 64; ++it) {
            float s = 0.0f, k = 0.0f;
            for (int c = 0; c < K4; c += 4) {
                float4 cv = *reinterpret_cast<const float4*>(&s_cand[wave][c]);
                if (cv.x > tau) { s += cv.x; k += 1.0f; }
                if (cv.y > tau) { s += cv.y; k += 1.0f; }
                if (cv.z > tau) { s += cv.z; k += 1.0f; }
                if (cv.w > tau) { s += cv.w; k += 1.0f; }
            }
            float ntau = (s - 1.0f) / k;   // k>=1: max is always > tau
            if (ntau == tau) break;
            tau = ntau;
        }
    } else {
        // ---- fallback (candidate overflow, ~never): full-register Newton ----
        for (int it = 0; it < 64; ++it) {
            float s = 0.0f, k = 0.0f;
#pragma unroll
            for (int j = 0; j < NV; ++j) {
                float a0 = v[j].x, a1 = v[j].y, a2 = v[j].z, a3 = v[j].w;
                if (a0 > tau) { s += a0; k += 1.0f; }
                if (a1 > tau) { s += a1; k += 1.0f; }
                if (a2 > tau) { s += a2; k += 1.0f; }
                if (a3 > tau) { s += a3; k += 1.0f; }
            }
#pragma unroll
            for (int off = 1; off < 64; off <<= 1) {
                s += __shfl_xor(s, off, 64);
                k += __shfl_xor(k, off, 64);
            }
            float ntau = (s - 1.0f) / k;
            if (ntau == tau) break;
            tau = ntau;
        }
    }

    // ---- output: max(x - tau, 0), coalesced float4 ----
#pragma unroll
    for (int j = 0; j < NV; ++j) {
        float4 o;
        o.x = fmaxf(v[j].x - tau, 0.0f);
        o.y = fmaxf(v[j].y - tau, 0.0f);
        o.z = fmaxf(v[j].z - tau, 0.0f);
        o.w = fmaxf(v[j].w - tau, 0.0f);
        reinterpret_cast<float4*>(outr)[lane + j * 64] = o;
    }
}

extern "C" void kernel_launch(void* const* d_in, const int* in_sizes, int n_in,
                              void* d_out, int out_size, void* d_ws, size_t ws_size,
                              hipStream_t stream) {
    const float* x = (const float*)d_in[0];
    float* out = (float*)d_out;
    const int nrows = in_sizes[0] / ROW_D;       // 16384, divisible by WPB
    sparsemax_wave_kernel<<<nrows / WPB, BLOCK, 0, stream>>>(x, out);
}